// Round 7
// baseline (342.954 us; speedup 1.0000x reference)
//
#include <hip/hip_runtime.h>
#include <cstdint>
#include <cstddef>

// LIF recurrent SNN, sinabs ThresholdSubtract.
//   B=32 independent batch rows -> 1 block per batch, state in registers.
//   Spikes ~4.4 sigma -> speculate "no spike in window", exact replay on hit.
// Round-14: R13 (WLEN=16, 63 windows) with the TAIL-ISSUE BUG fixed.
//   LEDGER: R7 3340cy/chunk, R11 3190, R12 3320 -- three different load
//   paths, same per-window cost => load path never the wall; per-window
//   skeleton carries ~2600cy fixed overhead. R13 halves window count:
//   predicted 63*(2600+16*90) ~ 254k cy ~ 106us scan vs measured 412k.
//   R13 FAILED (absmax 1.0): producer loop's `else GIS(ww+2,8)` was dead
//   code (ww+2 <= 61 always), so window 62 was never issued; the "window
//   61" epilogue published P0..P7 still holding window 61 rows -> last 8
//   steps ran on wrong x. R14 adds GIS(62,8) to the window-60 epilogue
//   (in flight one window before publication, same as steady state).
//   Discriminator unchanged: no time movement => cost is per-step.
#define B_       32
#define T_       1000
#define N_       1024
#define THREADS_ 512           // 8 waves: 4 consumer (tid<256) + 4 producer
#define CWAVES_  4
#define WLEN_    16            // steps per window
#define NW_      63            // 62 full windows + one 8-step tail
#define TAIL_    8
#define SLOT_BYTES_ 65536      // WLEN_*N_*4
#define ZBLOCKS_ 224           // total grid = 256 blocks = #CUs (1 block/CU)

typedef float v4f __attribute__((ext_vector_type(4)));

__device__ __forceinline__ v4f vmax4(v4f a, v4f b) {
  v4f r;
  r.x = fmaxf(a.x, b.x); r.y = fmaxf(a.y, b.y);
  r.z = fmaxf(a.z, b.z); r.w = fmaxf(a.w, b.w);
  return r;
}

// Inline-asm LDS read: opaque to SIInsertWaitcnts; ordered manually with
// lgkmcnt(0) + sched_barrier(0) (rule #18).
#define DSRD(dst, base, imm)                                                 \
  asm volatile("ds_read_b128 %0, %1 offset:" #imm : "=v"(dst) : "v"(base))

// Inline-asm global load: volatile asm is ordered among itself and against
// the volatile vmcnt asm -> issue points pinned; untracked by the waitcnt
// pass, so loads stay in flight across __syncthreads (by design).
#define GLD(dst, p)                                                          \
  asm volatile("global_load_dwordx4 %0, %1, off" : "=v"(dst) : "v"(p))

// Wait this wave's own outstanding asm loads (exact: per-wave counter).
#define VM0W                                                                 \
  do {                                                                       \
    asm volatile("s_waitcnt vmcnt(0)" ::: "memory");                         \
    __builtin_amdgcn_sched_barrier(0);                                       \
  } while (0)

// Issue rows [0,cnt) of window ww into P0..P{cnt-1} (this lane's v4 column).
#define GIS(ww, cnt)                                                         \
  do {                                                                       \
    const float* _pr = sbase + (size_t)(ww) * (WLEN_ * N_);                  \
    GLD(P0, _pr + 0 * N_);  GLD(P1, _pr + 1 * N_);                           \
    GLD(P2, _pr + 2 * N_);  GLD(P3, _pr + 3 * N_);                           \
    GLD(P4, _pr + 4 * N_);  GLD(P5, _pr + 5 * N_);                           \
    GLD(P6, _pr + 6 * N_);  GLD(P7, _pr + 7 * N_);                           \
    if ((cnt) == 16) {                                                       \
      GLD(P8,  _pr + 8 * N_);  GLD(P9,  _pr + 9 * N_);                       \
      GLD(P10, _pr + 10 * N_); GLD(P11, _pr + 11 * N_);                      \
      GLD(P12, _pr + 12 * N_); GLD(P13, _pr + 13 * N_);                      \
      GLD(P14, _pr + 14 * N_); GLD(P15, _pr + 15 * N_);                      \
    }                                                                        \
    __builtin_amdgcn_sched_barrier(0);  /* pin issue point */                \
  } while (0)

// Publish landed rows [0,cnt) of window ww to ring slot ww&1.
#define WRS(ww, cnt)                                                         \
  do {                                                                       \
    const int _sl = (ww) & 1;                                                \
    xring[_sl][0][col] = P0;  xring[_sl][1][col] = P1;                       \
    xring[_sl][2][col] = P2;  xring[_sl][3][col] = P3;                       \
    xring[_sl][4][col] = P4;  xring[_sl][5][col] = P5;                       \
    xring[_sl][6][col] = P6;  xring[_sl][7][col] = P7;                       \
    if ((cnt) == 16) {                                                       \
      xring[_sl][8][col]  = P8;  xring[_sl][9][col]  = P9;                   \
      xring[_sl][10][col] = P10; xring[_sl][11][col] = P11;                  \
      xring[_sl][12][col] = P12; xring[_sl][13][col] = P13;                  \
      xring[_sl][14][col] = P14; xring[_sl][15][col] = P15;                  \
    }                                                                        \
  } while (0)

#define SPEC_STEP(xf)                                                        \
  do {                                                                       \
    cmax = vmax4(cmax, st);                                                  \
    v4f _t = (xf) + rr;                                                      \
    st = st * 0.9f + 0.1f * _t;                                              \
    rr = brec;                                                               \
  } while (0)

// Consumer: process a 16-step window ww from ring slot ww&1.
#define PROCESS16(ww)                                                        \
  do {                                                                       \
    unsigned _a = xb + (unsigned)(((ww) & 1) * SLOT_BYTES_)                  \
                     + ((unsigned)tid << 4);                                 \
    v4f _x0,_x1,_x2,_x3,_x4,_x5,_x6,_x7,_x8,_x9,_xA,_xB,_xC,_xD,_xE,_xF;    \
    DSRD(_x0, _a, 0);     DSRD(_x1, _a, 4096);                               \
    DSRD(_x2, _a, 8192);  DSRD(_x3, _a, 12288);                              \
    DSRD(_x4, _a, 16384); DSRD(_x5, _a, 20480);                              \
    DSRD(_x6, _a, 24576); DSRD(_x7, _a, 28672);                              \
    DSRD(_x8, _a, 32768); DSRD(_x9, _a, 36864);                              \
    DSRD(_xA, _a, 40960); DSRD(_xB, _a, 45056);                              \
    DSRD(_xC, _a, 49152); DSRD(_xD, _a, 53248);                              \
    DSRD(_xE, _a, 57344); DSRD(_xF, _a, 61440);                              \
    asm volatile("s_waitcnt lgkmcnt(0)");                                    \
    __builtin_amdgcn_sched_barrier(0);  /* rule #18 */                       \
    v4f st = state, rr = rec, cmax = state;                                  \
    SPEC_STEP(_x0); SPEC_STEP(_x1); SPEC_STEP(_x2); SPEC_STEP(_x3);          \
    SPEC_STEP(_x4); SPEC_STEP(_x5); SPEC_STEP(_x6); SPEC_STEP(_x7);          \
    SPEC_STEP(_x8); SPEC_STEP(_x9); SPEC_STEP(_xA); SPEC_STEP(_xB);          \
    SPEC_STEP(_xC); SPEC_STEP(_xD); SPEC_STEP(_xE); SPEC_STEP(_xF);          \
    float _m = fmaxf(fmaxf(cmax.x, cmax.y), fmaxf(cmax.z, cmax.w));          \
    int _any = (_m >= 1.0f);                                                 \
    const int _p = (ww) & 1;                                                 \
    unsigned long long _wm = __ballot(_any);                                 \
    if (lane == 0) s_cmask[_p][wv] = _wm;                                    \
    __syncthreads();                                                         \
    unsigned long long _ab =                                                 \
        s_cmask[_p][0] | s_cmask[_p][1] | s_cmask[_p][2] | s_cmask[_p][3];   \
    if (_ab == 0ULL) { state = st; rec = brec; }                             \
    else { replay(ww, 16); }                                                 \
  } while (0)

// Consumer: the 8-step tail window (window 62, slot 0, rows 0..7).
#define PROCESS8(ww)                                                         \
  do {                                                                       \
    unsigned _a = xb + (unsigned)(((ww) & 1) * SLOT_BYTES_)                  \
                     + ((unsigned)tid << 4);                                 \
    v4f _x0,_x1,_x2,_x3,_x4,_x5,_x6,_x7;                                     \
    DSRD(_x0, _a, 0);     DSRD(_x1, _a, 4096);                               \
    DSRD(_x2, _a, 8192);  DSRD(_x3, _a, 12288);                              \
    DSRD(_x4, _a, 16384); DSRD(_x5, _a, 20480);                              \
    DSRD(_x6, _a, 24576); DSRD(_x7, _a, 28672);                              \
    asm volatile("s_waitcnt lgkmcnt(0)");                                    \
    __builtin_amdgcn_sched_barrier(0);                                       \
    v4f st = state, rr = rec, cmax = state;                                  \
    SPEC_STEP(_x0); SPEC_STEP(_x1); SPEC_STEP(_x2); SPEC_STEP(_x3);          \
    SPEC_STEP(_x4); SPEC_STEP(_x5); SPEC_STEP(_x6); SPEC_STEP(_x7);          \
    float _m = fmaxf(fmaxf(cmax.x, cmax.y), fmaxf(cmax.z, cmax.w));          \
    int _any = (_m >= 1.0f);                                                 \
    const int _p = (ww) & 1;                                                 \
    unsigned long long _wm = __ballot(_any);                                 \
    if (lane == 0) s_cmask[_p][wv] = _wm;                                    \
    __syncthreads();                                                         \
    unsigned long long _ab =                                                 \
        s_cmask[_p][0] | s_cmask[_p][1] | s_cmask[_p][2] | s_cmask[_p][3];   \
    if (_ab == 0ULL) { state = st; rec = brec; }                             \
    else { replay(ww, 8); }                                                  \
  } while (0)

__global__ __launch_bounds__(THREADS_, 1)
void lif_fused(const float* __restrict__ x, const float* __restrict__ w,
               const float* __restrict__ brec_g, float* __restrict__ out,
               unsigned long long* __restrict__ ws_rec,
               unsigned int* __restrict__ ws_cnt, int cap)
{
  // ---------------- zero path: blocks >= 32 clear the output ----------------
  if (blockIdx.x >= B_) {
    const size_t n4 = (size_t)B_ * T_ * N_ / 4;
    size_t i = (size_t)(blockIdx.x - B_) * THREADS_ + threadIdx.x;
    const size_t stride = (size_t)(gridDim.x - B_) * THREADS_;
    v4f* o4 = (v4f*)out;
    v4f z = (v4f)(0.f);
    for (; i < n4; i += stride) __builtin_nontemporal_store(z, &o4[i]);
    return;
  }

  // ---------------- lif path: blocks 0..31, one batch row each --------------
  const int b    = blockIdx.x;
  const int tid  = threadIdx.x;
  const int lane = tid & 63;
  const int wv   = tid >> 6;

  // x staging ring: 2 slots x 64KB, layout [slot][row 0..15][v4 col 0..255].
  // ~139.4KB total LDS -> hardware-enforced 1 block/CU (exclusivity).
  __shared__ v4f xring[2][WLEN_][N_ / 4];
  // Parity-double-buffered exchange: one barrier per window, no resets.
  __shared__ unsigned long long s_cmask[2][CWAVES_];
  __shared__ unsigned long long s_mask [2][CWAVES_];
  __shared__ v4f                s_val  [2][CWAVES_ * 64];
  __shared__ unsigned int       s_spkcnt;

  if (tid == 0) s_spkcnt = 0;   // visible to all after the prologue barrier

  const float* xg_base = x + (size_t)b * T_ * N_;

  if (wv >= CWAVES_) {
    // ------------------------- producer role ------------------------------
    // Wave pw covers v4-columns [pw*64, pw*64+64) of every row. Per window:
    // VM0W (window w+1 landed; issued one window ago, slack ~3000cy >> HBM
    // latency) -> 16 ds_write_b128 -> issue window w+2 -> barrier.
    const int pw  = wv - CWAVES_;            // 0..3
    const int col = (pw << 6) + lane;        // v4 column 0..255
    const float* sbase = xg_base + ((size_t)col << 2);

    auto replaycheck = [&](int ww, int klim) {
      const int p = ww & 1;
      unsigned long long ab =
          s_cmask[p][0] | s_cmask[p][1] | s_cmask[p][2] | s_cmask[p][3];
      if (ab != 0ULL) {
#pragma unroll 1
        for (int k = 0; k < klim; ++k) __syncthreads();  // mirror replay
      }
    };

    v4f P0,P1,P2,P3,P4,P5,P6,P7,P8,P9,P10,P11,P12,P13,P14,P15;

    // prologue: window 0 -> slot 0; window 1 left in flight
    GIS(0, 16);
    VM0W; WRS(0, 16);
    GIS(1, 16);
    __syncthreads();                      // prologue barrier (slot 0 ready)

#pragma unroll 1
    for (int ww = 0; ww < 60; ++ww) {     // windows 0..59; issue 2..61
      VM0W; WRS(ww + 1, 16);
      GIS(ww + 2, 16);
      __syncthreads();                    // barrier ww
      replaycheck(ww, 16);
    }
    // window 60: publish window 61, ISSUE window 62 (8 rows)  [R13 bugfix]
    VM0W; WRS(61, 16);
    GIS(62, 8);
    __syncthreads(); replaycheck(60, 16);
    // window 61: publish window 62 (8 rows)
    VM0W; WRS(62, 8);
    __syncthreads(); replaycheck(61, 16);
    // window 62: nothing to publish
    __syncthreads(); replaycheck(62, 8);
    __syncthreads();                      // epilogue barrier
    return;
  }

  // ------------------------- consumer role --------------------------------
  __builtin_amdgcn_s_setprio(1);          // T5: favor the latency-critical role
  const int n0 = tid << 2;                // this thread's 4 neurons

  // LDS byte offset of the ring base for the pinned asm ds_reads
  const unsigned xb =
      (unsigned)(uintptr_t)(__attribute__((address_space(3))) void*)xring;

  v4f state = (v4f)(0.f);
  v4f rec   = (v4f)(0.f);                 // initial carry rec = 0 (NOT b_rec)
  const v4f brec = *(const v4f*)(brec_g + n0);

  // Exact replay of window ww (rare): x comes from ring slot ww&1 (valid for
  // the whole replay -- producers are parked in the mirrored dummy barriers
  // and only overwrite this slot in window ww+1). Per-step spike exchange,
  // sparse rank-1 rec update, spike records.
  auto replay = [&](int ww, int klim) {
    v4f st = state;
    v4f r  = rec;
    const int sl = ww & 1;
#pragma unroll 1
    for (int k = 0; k < klim; ++k) {
      const int q = k & 1;
      v4f xv = xring[sl][k][tid];
      float tx = xv.x + r.x, ty = xv.y + r.y, tz = xv.z + r.z, tw = xv.w + r.w;
      float ax = (st.x > 0.f) ? floorf(st.x) : 0.f;
      float ay = (st.y > 0.f) ? floorf(st.y) : 0.f;
      float az = (st.z > 0.f) ? floorf(st.z) : 0.f;
      float aw = (st.w > 0.f) ? floorf(st.w) : 0.f;
      int ms = (ax != 0.f) | (ay != 0.f) | (az != 0.f) | (aw != 0.f);
      if (ms) {
        v4f v; v.x = ax; v.y = ay; v.z = az; v.w = aw;
        s_val[q][tid] = v;
        unsigned int off = (unsigned int)((ww * WLEN_ + k) * N_ + n0);
        float av[4] = {ax, ay, az, aw};
#pragma unroll
        for (int e = 0; e < 4; ++e) {
          if (av[e] != 0.f) {
            unsigned int idx = atomicAdd(&s_spkcnt, 1u);
            if ((int)idx < cap)
              ws_rec[(size_t)b * cap + idx] =
                  ((unsigned long long)(off + e) << 32) |
                  (unsigned long long)__float_as_uint(av[e]);
          }
        }
      }
      unsigned long long sm = __ballot(ms);
      if (lane == 0) s_mask[q][wv] = sm;
      st.x = (st.x - ax) * 0.9f + 0.1f * tx;
      st.y = (st.y - ay) * 0.9f + 0.1f * ty;
      st.z = (st.z - az) * 0.9f + 0.1f * tz;
      st.w = (st.w - aw) * 0.9f + 0.1f * tw;
      __syncthreads();                    // replay barrier (producers mirror)
      // sparse rank-1 rec update: rec[n] = b_rec[n] + sum_j act[j]*w[n][j]
      v4f racc = brec;
#pragma unroll 1
      for (int w2 = 0; w2 < CWAVES_; ++w2) {
        unsigned long long mm = s_mask[q][w2];
        while (mm) {
          int l = __builtin_ctzll(mm);
          mm &= mm - 1;
          int j = (w2 << 6) + l;
          v4f v = s_val[q][j];
          int jn = j << 2;
          if (v.x != 0.f) {
            racc.x += v.x * w[(size_t)(n0 + 0) * N_ + jn];
            racc.y += v.x * w[(size_t)(n0 + 1) * N_ + jn];
            racc.z += v.x * w[(size_t)(n0 + 2) * N_ + jn];
            racc.w += v.x * w[(size_t)(n0 + 3) * N_ + jn];
          }
          if (v.y != 0.f) {
            int j1 = jn + 1;
            racc.x += v.y * w[(size_t)(n0 + 0) * N_ + j1];
            racc.y += v.y * w[(size_t)(n0 + 1) * N_ + j1];
            racc.z += v.y * w[(size_t)(n0 + 2) * N_ + j1];
            racc.w += v.y * w[(size_t)(n0 + 3) * N_ + j1];
          }
          if (v.z != 0.f) {
            int j2 = jn + 2;
            racc.x += v.z * w[(size_t)(n0 + 0) * N_ + j2];
            racc.y += v.z * w[(size_t)(n0 + 1) * N_ + j2];
            racc.z += v.z * w[(size_t)(n0 + 2) * N_ + j2];
            racc.w += v.z * w[(size_t)(n0 + 3) * N_ + j2];
          }
          if (v.w != 0.f) {
            int j3 = jn + 3;
            racc.x += v.w * w[(size_t)(n0 + 0) * N_ + j3];
            racc.y += v.w * w[(size_t)(n0 + 1) * N_ + j3];
            racc.z += v.w * w[(size_t)(n0 + 2) * N_ + j3];
            racc.w += v.w * w[(size_t)(n0 + 3) * N_ + j3];
          }
        }
      }
      r = racc;
    }
    state = st;
    rec   = r;
  };

  __syncthreads();                        // prologue barrier (slot 0 ready)
#pragma unroll 1
  for (int ww = 0; ww < NW_ - 1; ++ww) {  // windows 0..61 (16 steps each)
    PROCESS16(ww);
  }
  PROCESS8(62);                           // tail window (steps 992..999)

  __syncthreads();                        // epilogue (all replay appends done)
  if (tid == 0) ws_cnt[b] = s_spkcnt;     // written unconditionally (ws poisoned)
}

// Apply the (few hundred) recorded spikes onto the zeroed output.
__global__ void scatter_spikes(const unsigned long long* __restrict__ rec,
                               const unsigned int* __restrict__ cnt,
                               float* __restrict__ out, int cap)
{
  int b = blockIdx.x;
  unsigned int n = cnt[b];
  if ((int)n > cap) n = cap;
  for (unsigned int i = threadIdx.x; i < n; i += blockDim.x) {
    unsigned long long r = rec[(size_t)b * cap + i];
    unsigned int off = (unsigned int)(r >> 32);
    float v = __uint_as_float((unsigned int)r);
    out[(size_t)b * (T_ * N_) + off] = v;
  }
}

extern "C" void kernel_launch(void* const* d_in, const int* in_sizes, int n_in,
                              void* d_out, int out_size, void* d_ws, size_t ws_size,
                              hipStream_t stream) {
  const float* x  = (const float*)d_in[0]; // [B,T,N] input_current
  const float* w  = (const float*)d_in[1]; // [N,N] w_rec (row-major [out,in])
  const float* br = (const float*)d_in[2]; // [N] b_rec
  float* out = (float*)d_out;              // [B,T,N] spikes

  // spike-record workspace layout: [32][cap] u64 records, then [32] u32 counts
  int cap = 4096;
  size_t need = (size_t)B_ * cap * 8 + B_ * 4;
  if (ws_size < need && ws_size > 256)
    cap = (int)((ws_size - 256) / ((size_t)B_ * 8));
  unsigned long long* rec = (unsigned long long*)d_ws;
  unsigned int* cnt = (unsigned int*)((char*)d_ws + (size_t)B_ * cap * 8);

  // blocks 0..31: sequential LIF scan (1 block/batch row, exclusive CU);
  // blocks 32..255: zero the output on the remaining CUs (1 block/CU).
  lif_fused<<<B_ + ZBLOCKS_, THREADS_, 0, stream>>>(x, w, br, out, rec, cnt, cap);
  scatter_spikes<<<B_, THREADS_, 0, stream>>>(rec, cnt, out, cap);
}

// Round 8
// 335.841 us; speedup vs baseline: 1.0212x; 1.0212x over previous
//
#include <hip/hip_runtime.h>
#include <cstdint>
#include <cstddef>

// LIF recurrent SNN, sinabs ThresholdSubtract.
//   B=32 independent batch rows -> 1 block per batch, state in registers.
//   Spikes ~4.4 sigma -> speculate "no spike in chunk", exact replay on hit.
// Round-15: R11 lif path (best measured: 166us scan) + HEATER experiment.
//   LEDGER: per-STEP cost ~400-440cy@2.4GHz-equivalent is INVARIANT across
//   R7 (serialized consumer loads, 3340cy/8-step), R11 (producer depth-4,
//   3190), R12 (4-window slack, 3320), R14 (16-step windows, half the
//   barriers/lgkm waits: 7100cy/16-step). R14 falsified fixed-per-window
//   overhead; R12 falsified producer latency; R13/R14 falsified barrier
//   count. The speculative step is ~12-16 straight-line register VALU ops
//   (~32cy issue, 5cy dep) -- nothing in the ISA costs 440cy for that.
//   Remaining coherent explanation: SCLK is NOT 2.4GHz here. After the
//   zero pass (~25us), 224/256 CUs idle and the 32 lif CUs are ~98%
//   stalled -> DPM plausibly drops SCLK ~4-6x. R15 tests it: zero-path
//   blocks become HEATERS (dense independent FMA) until all 32 lif blocks
//   signal completion via a device-scope atomic flag in ws (memset on the
//   stream pre-launch). lif path untouched -> clean A/B vs R11.
//   Pre-registered: TRUE -> scan ~45-90us; FALSE -> ~165-195us and R16
//   attacks step count (1-wave-per-batch, zero-barrier).
#define B_       32
#define T_       1000
#define N_       1024
#define THREADS_ 512           // 8 waves: 4 consumer (tid<256) + 4 producer
#define CWAVES_  4
#define CHUNK_   8
#define NCHUNK_  125           // 125*8 = 1000 steps
#define DEPTH_   4             // LDS ring slots
#define SLOT_BYTES_ 32768      // CHUNK_*N_*4
#define ZBLOCKS_ 224           // total grid = 256 blocks = #CUs (1 block/CU)

typedef float v4f __attribute__((ext_vector_type(4)));

__device__ __forceinline__ v4f vmax4(v4f a, v4f b) {
  v4f r;
  r.x = fmaxf(a.x, b.x); r.y = fmaxf(a.y, b.y);
  r.z = fmaxf(a.z, b.z); r.w = fmaxf(a.w, b.w);
  return r;
}

// Inline-asm LDS read: opaque to SIInsertWaitcnts; ordered manually with
// lgkmcnt(0) + sched_barrier(0) (rule #18).
#define DSRD(dst, base, imm)                                                 \
  asm volatile("ds_read_b128 %0, %1 offset:" #imm : "=v"(dst) : "v"(base))

// Inline-asm global load: volatile asm is ordered among itself and against
// the volatile vmcnt asms -> issue points are pinned; the waitcnt pass
// inserts nothing (asm is opaque), so counted vmcnt below is exact.
#define GLD(dst, p)                                                          \
  asm volatile("global_load_dwordx4 %0, %1, off" : "=v"(dst) : "v"(p))

#define VM8 asm volatile("s_waitcnt vmcnt(8)" ::: "memory")
#define VM0 asm volatile("s_waitcnt vmcnt(0)" ::: "memory")

// Issue one chunk's 8 row-loads for this producer lane (v4 column `col`).
#define GIS(b0,b1,b2,b3,b4,b5,b6,b7, cc)                                     \
  do {                                                                       \
    const float* _p = sbase + (size_t)(cc) * (CHUNK_ * N_);                  \
    GLD(b0, _p + 0 * N_); GLD(b1, _p + 1 * N_);                              \
    GLD(b2, _p + 2 * N_); GLD(b3, _p + 3 * N_);                              \
    GLD(b4, _p + 4 * N_); GLD(b5, _p + 5 * N_);                              \
    GLD(b6, _p + 6 * N_); GLD(b7, _p + 7 * N_);                              \
    __builtin_amdgcn_sched_barrier(0);  /* pin issue point */                \
  } while (0)

// Write a landed chunk from registers into its ring slot.
#define WRS(b0,b1,b2,b3,b4,b5,b6,b7, cc)                                     \
  do {                                                                       \
    const int _sl = (cc) & (DEPTH_ - 1);                                     \
    xring[_sl][0][col] = b0; xring[_sl][1][col] = b1;                        \
    xring[_sl][2][col] = b2; xring[_sl][3][col] = b3;                        \
    xring[_sl][4][col] = b4; xring[_sl][5][col] = b5;                        \
    xring[_sl][6][col] = b6; xring[_sl][7][col] = b7;                        \
  } while (0)

#define SPEC_STEP(xf)                                                        \
  do {                                                                       \
    cmax = vmax4(cmax, st);                                                  \
    v4f _t = (xf) + rr;                                                      \
    st = st * 0.9f + 0.1f * _t;                                              \
    rr = brec;                                                               \
  } while (0)

// Consumer: process chunk cc from ring slot cc&3 (written by producers two
// windows earlier). Speculative no-spike pass; ballot exchange; exact
// replay (rare). Exactly ONE __syncthreads per chunk (+8 in replay).
#define PROCESS(cc)                                                          \
  do {                                                                       \
    unsigned _a = xb + (unsigned)(((cc) & (DEPTH_ - 1)) * SLOT_BYTES_)       \
                     + ((unsigned)tid << 4);                                 \
    v4f _x0, _x1, _x2, _x3, _x4, _x5, _x6, _x7;                              \
    DSRD(_x0, _a, 0);     DSRD(_x1, _a, 4096);                               \
    DSRD(_x2, _a, 8192);  DSRD(_x3, _a, 12288);                              \
    DSRD(_x4, _a, 16384); DSRD(_x5, _a, 20480);                              \
    DSRD(_x6, _a, 24576); DSRD(_x7, _a, 28672);                              \
    asm volatile("s_waitcnt lgkmcnt(0)");                                    \
    __builtin_amdgcn_sched_barrier(0);  /* rule #18: no VALU hoist above */  \
    v4f st = state, rr = rec, cmax = state;                                  \
    SPEC_STEP(_x0); SPEC_STEP(_x1); SPEC_STEP(_x2); SPEC_STEP(_x3);          \
    SPEC_STEP(_x4); SPEC_STEP(_x5); SPEC_STEP(_x6); SPEC_STEP(_x7);          \
    float _m = fmaxf(fmaxf(cmax.x, cmax.y), fmaxf(cmax.z, cmax.w));          \
    int _any = (_m >= 1.0f);                                                 \
    const int _p = (cc) & 1;                                                 \
    unsigned long long _wm = __ballot(_any);                                 \
    if (lane == 0) s_cmask[_p][wv] = _wm;                                    \
    __syncthreads();                                                         \
    unsigned long long _ab =                                                 \
        s_cmask[_p][0] | s_cmask[_p][1] | s_cmask[_p][2] | s_cmask[_p][3];   \
    if (_ab == 0ULL) { state = st; rec = brec; }                             \
    else { replay(cc); }                                                     \
  } while (0)

__global__ __launch_bounds__(THREADS_, 1)
void lif_fused(const float* __restrict__ x, const float* __restrict__ w,
               const float* __restrict__ brec_g, float* __restrict__ out,
               unsigned long long* __restrict__ ws_rec,
               unsigned int* __restrict__ ws_cnt, int cap,
               unsigned int* __restrict__ done)
{
  // ---------------- zero+heater path: blocks >= 32 ----------------
  if (blockIdx.x >= B_) {
    __shared__ unsigned s_hflag;
    const size_t n4 = (size_t)B_ * T_ * N_ / 4;
    size_t i = (size_t)(blockIdx.x - B_) * THREADS_ + threadIdx.x;
    const size_t stride = (size_t)(gridDim.x - B_) * THREADS_;
    v4f* o4 = (v4f*)out;
    v4f z = (v4f)(0.f);
    for (; i < n4; i += stride) __builtin_nontemporal_store(z, &o4[i]);

    // ---- heater: keep SCLK up while the lif blocks run ----
    // Dense independent FMA on the otherwise-idle 224 CUs. Exit when all
    // 32 lif blocks have bumped `done` (device-scope atomic; flag memset
    // to 0 on the stream before launch). Poll ~every 4096 FMA (3-20us);
    // 224 pollers on one line = tens of M atomics/s, on lines the lif
    // path never touches. All 256 blocks are co-resident (139KB LDS ->
    // 1 block/CU), so lif progress never depends on heater exit.
    float h0 = (float)(threadIdx.x + 1) * 1.000001f;
    float h1 = h0 * 1.3f, h2 = h0 * 1.7f, h3 = h0 * 2.9f;
    for (;;) {
      if (threadIdx.x == 0) s_hflag = atomicAdd(done, 0u);
      __syncthreads();
      if (s_hflag >= B_) break;
#pragma unroll 32
      for (int it = 0; it < 1024; ++it) {
        h0 = __builtin_fmaf(h0, 1.0000001f, 1e-7f);
        h1 = __builtin_fmaf(h1, 1.0000001f, 1e-7f);
        h2 = __builtin_fmaf(h2, 1.0000001f, 1e-7f);
        h3 = __builtin_fmaf(h3, 1.0000001f, 1e-7f);
      }
      asm volatile("" :: "v"(h0), "v"(h1), "v"(h2), "v"(h3));
      __syncthreads();
    }
    return;
  }

  // ---------------- lif path: blocks 0..31, one batch row each --------------
  const int b    = blockIdx.x;
  const int tid  = threadIdx.x;
  const int lane = tid & 63;
  const int wv   = tid >> 6;

  // x staging ring: 4 slots x 32KB, layout [slot][row k][v4 column 0..255].
  // 139KB total LDS -> hardware-enforced 1 block/CU (exclusivity).
  __shared__ v4f xring[DEPTH_][CHUNK_][N_ / 4];
  // Parity-double-buffered exchange: one barrier per chunk/step, no resets.
  __shared__ unsigned long long s_cmask[2][CWAVES_];
  __shared__ unsigned long long s_mask [2][CWAVES_];
  __shared__ v4f                s_val  [2][CWAVES_ * 64];
  __shared__ unsigned int       s_spkcnt;

  if (tid == 0) s_spkcnt = 0;   // visible to all after the prologue barrier

  const float* xg_base = x + (size_t)b * T_ * N_;

  if (wv >= CWAVES_) {
    // ------------------------- producer role ------------------------------
    // Wave pw owns v4-columns [pw*64, pw*64+64) of EVERY row (matches the
    // consumer read layout xring[sl][k][tid]). Unroll x2, named buffers A/B.
    // Steady state at window c (even): A = chunk c+2 in flight, B = chunk
    // c+3 in flight (16 loads outstanding). vmcnt(8) retires the oldest 8.
    const int pw  = wv - CWAVES_;            // 0..3 = column-segment index
    const int col = (pw << 6) + lane;        // v4 column 0..255
    const float* sbase = xg_base + ((size_t)col << 2);

    auto replaycheck = [&](int c) {
      const int p = c & 1;
      unsigned long long ab =
          s_cmask[p][0] | s_cmask[p][1] | s_cmask[p][2] | s_cmask[p][3];
      if (ab != 0ULL) {
#pragma unroll 1
        for (int k = 0; k < CHUNK_; ++k) __syncthreads();  // mirror replay
      }
    };

    v4f A0, A1, A2, A3, A4, A5, A6, A7;
    v4f B0, B1, B2, B3, B4, B5, B6, B7;

    // prologue: fill slots 0,1; leave chunks 2 (A) and 3 (B) in flight
    GIS(A0,A1,A2,A3,A4,A5,A6,A7, 0);
    GIS(B0,B1,B2,B3,B4,B5,B6,B7, 1);
    VM8; WRS(A0,A1,A2,A3,A4,A5,A6,A7, 0);
    GIS(A0,A1,A2,A3,A4,A5,A6,A7, 2);
    VM8; WRS(B0,B1,B2,B3,B4,B5,B6,B7, 1);
    GIS(B0,B1,B2,B3,B4,B5,B6,B7, 3);
    __syncthreads();                      // prologue barrier (slots 0,1 ready)

#pragma unroll 1
    for (int c = 0; c < NCHUNK_ - 1; c += 2) {   // windows c, c+1; c even
      // ---- window c: write A (chunk c+2), refill A <- chunk c+4 ----
      if (c <= NCHUNK_ - 5) {                    // c <= 120
        VM8; WRS(A0,A1,A2,A3,A4,A5,A6,A7, c + 2);
        GIS(A0,A1,A2,A3,A4,A5,A6,A7, c + 4);
      } else {                                   // c == 122: last write, drain
        VM0; WRS(A0,A1,A2,A3,A4,A5,A6,A7, c + 2);
      }
      __syncthreads();                    // barrier c
      replaycheck(c);
      // ---- window c+1: write B (chunk c+3), refill B <- chunk c+5 ----
      if (c <= NCHUNK_ - 5) {                    // c <= 120 -> chunk c+3 valid
        VM8; WRS(B0,B1,B2,B3,B4,B5,B6,B7, c + 3);
        if (c <= NCHUNK_ - 7)                    // c <= 118 -> chunk c+5 valid
          GIS(B0,B1,B2,B3,B4,B5,B6,B7, c + 5);
      }
      __syncthreads();                    // barrier c+1
      replaycheck(c + 1);
    }
    // window 124: nothing to write/issue
    __syncthreads();                      // barrier 124
    replaycheck(NCHUNK_ - 1);
    __syncthreads();                      // epilogue barrier
    return;
  }

  // ------------------------- consumer role --------------------------------
  __builtin_amdgcn_s_setprio(1);          // T5: favor the latency-critical role
  const int n0 = tid << 2;                // this thread's 4 neurons

  // LDS byte offset of the ring base for the pinned asm ds_reads
  const unsigned xb =
      (unsigned)(uintptr_t)(__attribute__((address_space(3))) void*)xring;

  v4f state = (v4f)(0.f);
  v4f rec   = (v4f)(0.f);                 // initial carry rec = 0 (NOT b_rec)
  const v4f brec = *(const v4f*)(brec_g + n0);

  // Exact replay of chunk cc (rare): x comes from ring slot cc&3 (valid until
  // chunk c+4 is written in window c+2; producers are parked in the matching
  // dummy barriers during replay). Per-step spike exchange, sparse rank-1
  // rec update, spike records.
  auto replay = [&](int cc) {
    v4f st = state;
    v4f r  = rec;
    const int sl = cc & (DEPTH_ - 1);
#pragma unroll 1
    for (int k = 0; k < CHUNK_; ++k) {
      const int q = k & 1;
      v4f xv = xring[sl][k][tid];
      float tx = xv.x + r.x, ty = xv.y + r.y, tz = xv.z + r.z, tw = xv.w + r.w;
      float ax = (st.x > 0.f) ? floorf(st.x) : 0.f;
      float ay = (st.y > 0.f) ? floorf(st.y) : 0.f;
      float az = (st.z > 0.f) ? floorf(st.z) : 0.f;
      float aw = (st.w > 0.f) ? floorf(st.w) : 0.f;
      int ms = (ax != 0.f) | (ay != 0.f) | (az != 0.f) | (aw != 0.f);
      if (ms) {
        v4f v; v.x = ax; v.y = ay; v.z = az; v.w = aw;
        s_val[q][tid] = v;
        unsigned int off = (unsigned int)((cc * CHUNK_ + k) * N_ + n0);
        float av[4] = {ax, ay, az, aw};
#pragma unroll
        for (int e = 0; e < 4; ++e) {
          if (av[e] != 0.f) {
            unsigned int idx = atomicAdd(&s_spkcnt, 1u);
            if ((int)idx < cap)
              ws_rec[(size_t)b * cap + idx] =
                  ((unsigned long long)(off + e) << 32) |
                  (unsigned long long)__float_as_uint(av[e]);
          }
        }
      }
      unsigned long long sm = __ballot(ms);
      if (lane == 0) s_mask[q][wv] = sm;
      st.x = (st.x - ax) * 0.9f + 0.1f * tx;
      st.y = (st.y - ay) * 0.9f + 0.1f * ty;
      st.z = (st.z - az) * 0.9f + 0.1f * tz;
      st.w = (st.w - aw) * 0.9f + 0.1f * tw;
      __syncthreads();                    // replay barrier (producers mirror)
      // sparse rank-1 rec update: rec[n] = b_rec[n] + sum_j act[j]*w[n][j]
      v4f racc = brec;
#pragma unroll 1
      for (int w2 = 0; w2 < CWAVES_; ++w2) {
        unsigned long long mm = s_mask[q][w2];
        while (mm) {
          int l = __builtin_ctzll(mm);
          mm &= mm - 1;
          int j = (w2 << 6) + l;
          v4f v = s_val[q][j];
          int jn = j << 2;
          if (v.x != 0.f) {
            racc.x += v.x * w[(size_t)(n0 + 0) * N_ + jn];
            racc.y += v.x * w[(size_t)(n0 + 1) * N_ + jn];
            racc.z += v.x * w[(size_t)(n0 + 2) * N_ + jn];
            racc.w += v.x * w[(size_t)(n0 + 3) * N_ + jn];
          }
          if (v.y != 0.f) {
            int j1 = jn + 1;
            racc.x += v.y * w[(size_t)(n0 + 0) * N_ + j1];
            racc.y += v.y * w[(size_t)(n0 + 1) * N_ + j1];
            racc.z += v.y * w[(size_t)(n0 + 2) * N_ + j1];
            racc.w += v.y * w[(size_t)(n0 + 3) * N_ + j1];
          }
          if (v.z != 0.f) {
            int j2 = jn + 2;
            racc.x += v.z * w[(size_t)(n0 + 0) * N_ + j2];
            racc.y += v.z * w[(size_t)(n0 + 1) * N_ + j2];
            racc.z += v.z * w[(size_t)(n0 + 2) * N_ + j2];
            racc.w += v.z * w[(size_t)(n0 + 3) * N_ + j2];
          }
          if (v.w != 0.f) {
            int j3 = jn + 3;
            racc.x += v.w * w[(size_t)(n0 + 0) * N_ + j3];
            racc.y += v.w * w[(size_t)(n0 + 1) * N_ + j3];
            racc.z += v.w * w[(size_t)(n0 + 2) * N_ + j3];
            racc.w += v.w * w[(size_t)(n0 + 3) * N_ + j3];
          }
        }
      }
      r = racc;
    }
    state = st;
    rec   = r;
  };

  __syncthreads();                        // prologue barrier (slots 0,1 ready)
#pragma unroll 1
  for (int c = 0; c < NCHUNK_; ++c) {
    PROCESS(c);
  }

  __syncthreads();                        // epilogue (all replay appends done)
  if (tid == 0) {
    ws_cnt[b] = s_spkcnt;                 // written unconditionally (ws poisoned)
    atomicAdd(done, 1u);                  // release one heater "vote"
  }
}

// Apply the (few hundred) recorded spikes onto the zeroed output.
__global__ void scatter_spikes(const unsigned long long* __restrict__ rec,
                               const unsigned int* __restrict__ cnt,
                               float* __restrict__ out, int cap)
{
  int b = blockIdx.x;
  unsigned int n = cnt[b];
  if ((int)n > cap) n = cap;
  for (unsigned int i = threadIdx.x; i < n; i += blockDim.x) {
    unsigned long long r = rec[(size_t)b * cap + i];
    unsigned int off = (unsigned int)(r >> 32);
    float v = __uint_as_float((unsigned int)r);
    out[(size_t)b * (T_ * N_) + off] = v;
  }
}

extern "C" void kernel_launch(void* const* d_in, const int* in_sizes, int n_in,
                              void* d_out, int out_size, void* d_ws, size_t ws_size,
                              hipStream_t stream) {
  const float* x  = (const float*)d_in[0]; // [B,T,N] input_current
  const float* w  = (const float*)d_in[1]; // [N,N] w_rec (row-major [out,in])
  const float* br = (const float*)d_in[2]; // [N] b_rec
  float* out = (float*)d_out;              // [B,T,N] spikes

  // ws layout: [32][cap] u64 records, [32] u32 counts, 1 u32 done-flag
  int cap = 4096;
  size_t need = (size_t)B_ * cap * 8 + B_ * 4 + 4;
  if (ws_size < need && ws_size > 256)
    cap = (int)((ws_size - 256 - 4) / ((size_t)B_ * 8));
  unsigned long long* rec = (unsigned long long*)d_ws;
  unsigned int* cnt = (unsigned int*)((char*)d_ws + (size_t)B_ * cap * 8);
  unsigned int* done = cnt + B_;

  // Reset the heater-exit flag (stream-ordered, graph-capturable).
  hipMemsetAsync(done, 0, 4, stream);

  // blocks 0..31: sequential LIF scan (1 block/batch row, exclusive CU);
  // blocks 32..255: zero the output, then heat their CU until lif done.
  lif_fused<<<B_ + ZBLOCKS_, THREADS_, 0, stream>>>(x, w, br, out, rec, cnt,
                                                    cap, done);
  scatter_spikes<<<B_, THREADS_, 0, stream>>>(rec, cnt, out, cap);
}